// Round 10
// baseline (59.875 us; speedup 1.0000x reference)
//
#include <hip/hip_runtime.h>

#define DIM 128
#define NVOX (DIM*DIM*DIM)
#define TD 8
#define TH 8
#define TW 16
#define HD 10
#define HH 10
#define HW 18
#define HALO (HD*HH*HW)   // 1800
#define PLANE 1808        // + guard cells (zeroed), keeps dword alignment

typedef __attribute__((ext_vector_type(8))) __bf16 bf16x8;
typedef __attribute__((ext_vector_type(4))) float  f32x4;
typedef __attribute__((ext_vector_type(4))) unsigned uintx4;
typedef __attribute__((ext_vector_type(2))) _Float16 half2t;

static __device__ __host__ __forceinline__ unsigned short f2bf(float f) {
    union { float f; unsigned u; } v; v.f = f;
    unsigned r = v.u + 0x7FFFu + ((v.u >> 16) & 1u);   // RNE
    return (unsigned short)(r >> 16);
}

// tap table: lane-group g, slot j -> (row 0..8, cell 0..2) or pad(false)
// rows: W0r={0,3,5,8} W1r={1,4,6,7} W2r={2,2,7,7}; g3's W1 window is shifted +2 cells.
static __device__ __forceinline__ bool slot_tap(int g, int j, int& row, int& cell) {
    const int W0r[4] = {0,3,5,8};
    const int W1r[4] = {1,4,6,7};
    const int W2r[4] = {2,2,7,7};
    switch (j) {
    case 0: row = W0r[g]; cell = 0; return true;
    case 1: row = W0r[g]; cell = 1; return true;
    case 2: row = W0r[g]; cell = 2; return true;
    case 3: if (g == 3) { row = 7; cell = 2; } else { row = W1r[g]; cell = 0; } return true;
    case 4: if (g == 3) return false; row = W1r[g]; cell = 1; return true;
    case 5: if (g == 3) return false; row = W1r[g]; cell = 2; return true;
    case 6: if (g == 1) { row = 2; cell = 2; return true; }
            if (g == 3) return false; row = W2r[g]; cell = 0; return true;
    default: if (g == 0) { row = 2; cell = 1; return true; }
             if (g == 2) { row = 7; cell = 1; return true; }
             return false;
    }
}

// Wa[(m,T,lane,i)] = bf16 W[ch=T*16+(lane&15)][m, tap(g=lane>>4, j=i)] or 0
__global__ void prep_kernel(const float* __restrict__ W, const float* __restrict__ bias,
                            unsigned short* __restrict__ Wa, float* __restrict__ bias32) {
    int idx = blockIdx.x * 256 + threadIdx.x;
    if (idx < 3072) {
        int i  = idx & 7;
        int l  = (idx >> 3) & 63;
        int T  = (idx >> 9) & 1;
        int mm = idx >> 10;
        int ch = T * 16 + (l & 15);
        int g  = l >> 4;
        int row, cell;
        float w = 0.f;
        if (ch < 27 && slot_tap(g, i, row, cell)) {
            int di = row / 3, dj = row % 3;
            w = W[ch * 81 + mm * 27 + di * 9 + dj * 3 + cell];
        }
        Wa[idx] = f2bf(w);
    } else if (idx < 3072 + 32) {
        int c = idx - 3072;
        bias32[c] = (c < 27) ? bias[c] : 0.f;
    }
}

static __device__ __forceinline__ float red16_32(float y) {
#if __has_builtin(__builtin_amdgcn_permlane16_swap) && __has_builtin(__builtin_amdgcn_permlane32_swap)
    typedef unsigned uv2 __attribute__((ext_vector_type(2)));
    unsigned a = __float_as_uint(y);
    uv2 r = __builtin_amdgcn_permlane16_swap(a, a, false, false);
    y = __uint_as_float(r[0]) + __uint_as_float(r[1]);
    a = __float_as_uint(y);
    uv2 q = __builtin_amdgcn_permlane32_swap(a, a, false, false);
    return __uint_as_float(q[0]) + __uint_as_float(q[1]);
#else
    y += __shfl_xor(y, 16);
    y += __shfl_xor(y, 32);
    return y;
#endif
}

__global__ __launch_bounds__(512) void invo_mfma_kernel(
    const float* __restrict__ img,   // (3, D,H,W) f32
    const float* __restrict__ x,     // (4, 1, D,H,W) f32
    const unsigned short* __restrict__ Wa,
    const float* __restrict__ bias32,
    float* __restrict__ out)         // (4, 1, D,H,W) f32
{
    __shared__ unsigned short sImg[3 * PLANE];   // bf16 halo planes [m][cell]
    __shared__ uint2 sX2[HALO];                  // f16 [cell][b01, b23]

    // XCD-aware bijective swizzle: 2048 blocks = 8 XCDs x 256-chunk
    const unsigned orig = blockIdx.x;
    const unsigned wg = ((orig & 7u) << 8) | (orig >> 3);
    const int w0 = (wg & 7) * TW;
    const int h0 = ((wg >> 3) & 15) * TH;
    const int d0 = (wg >> 7) * TD;
    const int tid = threadIdx.x;

    // ---- stage halos ----
    for (int idx = tid; idx < PLANE; idx += 512) {
        if (idx < HALO) {
            int lw = idx % HW;
            int t  = idx / HW;
            int lh = t % HH;
            int ld = t / HH;
            int gd = d0 - 1 + ld, gh = h0 - 1 + lh, gw = w0 - 1 + lw;
            bool ok = (unsigned)gd < DIM && (unsigned)gh < DIM && (unsigned)gw < DIM;
            long gi = ((long)gd * DIM + gh) * DIM + gw;
            float i0 = 0, i1 = 0, i2 = 0, x0 = 0, x1 = 0, x2 = 0, x3 = 0;
            if (ok) {
                i0 = img[gi]; i1 = img[NVOX + gi]; i2 = img[2 * NVOX + gi];
                x0 = x[gi]; x1 = x[NVOX + gi]; x2 = x[2 * NVOX + gi]; x3 = x[3 * NVOX + gi];
            }
            // hw bf16 pack (RNE, same as f2bf) -- 2 instr instead of ~13
            unsigned i01, i22;
            asm("v_cvt_pk_bf16_f32 %0, %1, %2" : "=v"(i01) : "v"(i0), "v"(i1));
            asm("v_cvt_pk_bf16_f32 %0, %1, %2" : "=v"(i22) : "v"(i2), "v"(i2));
            sImg[idx]             = (unsigned short)(i01 & 0xffffu);
            sImg[PLANE + idx]     = (unsigned short)(i01 >> 16);
            sImg[2 * PLANE + idx] = (unsigned short)(i22 & 0xffffu);
            unsigned p01 = __builtin_bit_cast(unsigned, __builtin_amdgcn_cvt_pkrtz(x0, x1));
            unsigned p23 = __builtin_bit_cast(unsigned, __builtin_amdgcn_cvt_pkrtz(x2, x3));
            sX2[idx] = make_uint2(p01, p23);
        } else {
            sImg[idx] = 0; sImg[PLANE + idx] = 0; sImg[2 * PLANE + idx] = 0;  // guard
        }
    }
    __syncthreads();

    const int lane = tid & 63;
    const int wv   = tid >> 6;       // wave 0..7
    const int v    = lane & 15;      // voxel (w) within 16-run
    const int g    = lane >> 4;      // k-group 0..3
    const unsigned b = 2u * (v & 1);

    // v_perm selectors for B-frag gather (hi, lo sources; code = byte pos in 8B window)
    unsigned sel0 = b | ((b + 1) << 8) | ((b + 2) << 16) | ((b + 3) << 24);
    unsigned sel1 = (4 + b) | ((5 + b) << 8) | (b << 16) | ((b + 1) << 24);
    unsigned sel2 = (b + 2) | ((b + 3) << 8) | ((b + 4) << 16) | ((b + 5) << 24);
    unsigned sel3 = (g == 1) ? ((b + 4) | ((b + 5) << 8) | ((b + 4) << 16) | ((b + 5) << 24)) : sel0;

    // window rows per group
    const int w0r = (g == 0) ? 0 : (g == 1) ? 3 : (g == 2) ? 5 : 8;
    const int w1r = (g == 0) ? 1 : (g == 1) ? 4 : (g == 2) ? 6 : 7;
    const int w2r = (g < 2) ? 2 : 7;

    const int e  = v & ~1;
    const int e1 = (g == 3) ? ((v + 2) & ~1) : e;   // g3's W1 window shifted +2 cells

    // m=0 window dword offsets only; m=1,2 become compile-time +904/+1808 dword
    // immediates on the ds_read (folds into the 16-bit offset field)
    int wkd0[3];
    wkd0[0] = ((w0r / 3) * (HH * HW) + (w0r % 3) * HW + e) / 2;
    wkd0[1] = ((w1r / 3) * (HH * HW) + (w1r % 3) * HW + e1) / 2;
    wkd0[2] = ((w2r / 3) * (HH * HW) + (w2r % 3) * HW + e) / 2;

    // apply-step x cell offsets for this lane's channels
    int xo0[4], xo1[4];
    #pragma unroll
    for (int r = 0; r < 4; ++r) {
        int c = 4 * g + r;
        { int i3 = c / 9, rr = c - 9 * i3, j3 = rr / 3, k3 = rr - 3 * j3;
          xo0[r] = i3 * (HH * HW) + j3 * HW + k3; }
        int c1 = 16 + 4 * g + r;
        if (c1 < 27) {
            int i3 = c1 / 9, rr = c1 - 9 * i3, j3 = rr / 3, k3 = rr - 3 * j3;
            xo1[r] = i3 * (HH * HW) + j3 * HW + k3;
        } else xo1[r] = 0;
    }

    // hoist A fragments + bias
    bf16x8 afrag[3][2];
    #pragma unroll
    for (int m = 0; m < 3; ++m)
        #pragma unroll
        for (int T = 0; T < 2; ++T)
            afrag[m][T] = *reinterpret_cast<const bf16x8*>(&Wa[((m * 2 + T) * 64 + lane) * 8]);
    f32x4 b0 = *reinterpret_cast<const f32x4*>(&bias32[4 * g]);
    f32x4 b1 = *reinterpret_cast<const f32x4*>(&bias32[16 + 4 * g]);

    const unsigned* s32 = reinterpret_cast<const unsigned*>(sImg);

    #pragma unroll 2
    for (int it = 0; it < 8; ++it) {
        const int run = wv * 8 + it;             // 0..63; ld = wv, lh = it
        const int ld = run >> 3, lh = run & 7;
        const int rdw   = (ld * HH + lh) * (HW / 2);
        const int xbase = (ld * HH + lh) * HW + v;

        f32x4 acc0 = b0, acc1 = b1;    // bias folded into accumulator init
        #pragma unroll
        for (int m = 0; m < 3; ++m) {
            const int mo = m * (PLANE / 2);      // compile-time: 0, 904, 1808 dwords
            unsigned lo0 = s32[rdw + wkd0[0] + mo], hi0 = s32[rdw + wkd0[0] + mo + 1];
            unsigned lo1 = s32[rdw + wkd0[1] + mo], hi1 = s32[rdw + wkd0[1] + mo + 1];
            unsigned lo2 = s32[rdw + wkd0[2] + mo], hi2 = s32[rdw + wkd0[2] + mo + 1];
            unsigned d0p = __builtin_amdgcn_perm(hi0, lo0, sel0);
            unsigned d1p = __builtin_amdgcn_perm(hi0, lo1, sel1);
            unsigned d2p = __builtin_amdgcn_perm(hi1, lo1, sel2);
            unsigned d3p = __builtin_amdgcn_perm(hi2, lo2, sel3);
            uintx4 uu = {d0p, d1p, d2p, d3p};
            bf16x8 bfrag = __builtin_bit_cast(bf16x8, uu);
            acc0 = __builtin_amdgcn_mfma_f32_16x16x32_bf16(afrag[m][0], bfrag, acc0, 0, 0, 0);
            acc1 = __builtin_amdgcn_mfma_f32_16x16x32_bf16(afrag[m][1], bfrag, acc1, 0, 0, 0);
        }

        // apply: y[b] = sum_ch K[ch] * x[b, p+off(ch)]  -- f16 dot2 path
        float y0 = 0, y1 = 0, y2 = 0, y3 = 0;
#if __has_builtin(__builtin_amdgcn_fdot2)
        #pragma unroll
        for (int r = 0; r < 4; r += 2) {
            {
                half2t kp = __builtin_bit_cast(half2t, __builtin_amdgcn_cvt_pkrtz(acc0[r], acc0[r + 1]));
                uint2 uA = sX2[xbase + xo0[r]];
                uint2 uB = sX2[xbase + xo0[r + 1]];
                unsigned p0 = __builtin_amdgcn_perm(uB.x, uA.x, 0x05040100u);
                unsigned p1 = __builtin_amdgcn_perm(uB.x, uA.x, 0x07060302u);
                unsigned p2 = __builtin_amdgcn_perm(uB.y, uA.y, 0x05040100u);
                unsigned p3 = __builtin_amdgcn_perm(uB.y, uA.y, 0x07060302u);
                y0 = __builtin_amdgcn_fdot2(kp, __builtin_bit_cast(half2t, p0), y0, false);
                y1 = __builtin_amdgcn_fdot2(kp, __builtin_bit_cast(half2t, p1), y1, false);
                y2 = __builtin_amdgcn_fdot2(kp, __builtin_bit_cast(half2t, p2), y2, false);
                y3 = __builtin_amdgcn_fdot2(kp, __builtin_bit_cast(half2t, p3), y3, false);
            }
            {
                half2t kp = __builtin_bit_cast(half2t, __builtin_amdgcn_cvt_pkrtz(acc1[r], acc1[r + 1]));
                uint2 uA = sX2[xbase + xo1[r]];
                uint2 uB = sX2[xbase + xo1[r + 1]];
                unsigned p0 = __builtin_amdgcn_perm(uB.x, uA.x, 0x05040100u);
                unsigned p1 = __builtin_amdgcn_perm(uB.x, uA.x, 0x07060302u);
                unsigned p2 = __builtin_amdgcn_perm(uB.y, uA.y, 0x05040100u);
                unsigned p3 = __builtin_amdgcn_perm(uB.y, uA.y, 0x07060302u);
                y0 = __builtin_amdgcn_fdot2(kp, __builtin_bit_cast(half2t, p0), y0, false);
                y1 = __builtin_amdgcn_fdot2(kp, __builtin_bit_cast(half2t, p1), y1, false);
                y2 = __builtin_amdgcn_fdot2(kp, __builtin_bit_cast(half2t, p2), y2, false);
                y3 = __builtin_amdgcn_fdot2(kp, __builtin_bit_cast(half2t, p3), y3, false);
            }
        }
#else
        #pragma unroll
        for (int r = 0; r < 4; ++r) {
            float K0 = acc0[r];
            float K1 = acc1[r];
            uint2 u0 = sX2[xbase + xo0[r]];
            uint2 u1 = sX2[xbase + xo1[r]];
            half2t a0 = __builtin_bit_cast(half2t, u0.x), a1 = __builtin_bit_cast(half2t, u0.y);
            half2t c0 = __builtin_bit_cast(half2t, u1.x), c1 = __builtin_bit_cast(half2t, u1.y);
            y0 = fmaf(K0, (float)a0[0], y0); y1 = fmaf(K0, (float)a0[1], y1);
            y2 = fmaf(K0, (float)a1[0], y2); y3 = fmaf(K0, (float)a1[1], y3);
            y0 = fmaf(K1, (float)c0[0], y0); y1 = fmaf(K1, (float)c0[1], y1);
            y2 = fmaf(K1, (float)c1[0], y2); y3 = fmaf(K1, (float)c1[1], y3);
        }
#endif

        y0 = red16_32(y0); y1 = red16_32(y1); y2 = red16_32(y2); y3 = red16_32(y3);

        const long p = ((long)(d0 + ld) * DIM + (h0 + lh)) * DIM + (w0 + v);
        float yv = (g == 0) ? y0 : (g == 1) ? y1 : (g == 2) ? y2 : y3;
        out[(long)g * NVOX + p] = yv;
    }
}

extern "C" void kernel_launch(void* const* d_in, const int* in_sizes, int n_in,
                              void* d_out, int out_size, void* d_ws, size_t ws_size,
                              hipStream_t stream) {
    const float* img  = (const float*)d_in[0];
    const float* x    = (const float*)d_in[1];
    const float* W    = (const float*)d_in[2];
    const float* bias = (const float*)d_in[3];
    float* out = (float*)d_out;

    unsigned short* Wa = (unsigned short*)d_ws;        // 3072 u16
    float* bias32 = (float*)((char*)d_ws + 6144);      // 32 f32

    prep_kernel<<<13, 256, 0, stream>>>(W, bias, Wa, bias32);

    invo_mfma_kernel<<<2048, 512, 0, stream>>>(img, x, Wa, bias32, out);
}

// Round 11
// 48.216 us; speedup vs baseline: 1.2418x; 1.2418x over previous
//
#include <hip/hip_runtime.h>

#define DIM 128
#define NVOX (DIM*DIM*DIM)
#define TD 8
#define TH 8
#define TW 16
#define HD 10
#define HH 10
#define HW 18
#define HALO (HD*HH*HW)   // 1800
#define PLANE 1808        // + guard cells (zeroed), keeps dword alignment

typedef __attribute__((ext_vector_type(8))) __bf16 bf16x8;
typedef __attribute__((ext_vector_type(4))) float  f32x4;
typedef __attribute__((ext_vector_type(4))) unsigned uintx4;
typedef __attribute__((ext_vector_type(2))) _Float16 half2t;

static __device__ __host__ __forceinline__ unsigned short f2bf(float f) {
    union { float f; unsigned u; } v; v.f = f;
    unsigned r = v.u + 0x7FFFu + ((v.u >> 16) & 1u);   // RNE
    return (unsigned short)(r >> 16);
}

// tap table: lane-group g, slot j -> (row 0..8, cell 0..2) or pad(false)
// rows: W0r={0,3,5,8} W1r={1,4,6,7} W2r={2,2,7,7}; g3's W1 window is shifted +2 cells.
static __device__ __forceinline__ bool slot_tap(int g, int j, int& row, int& cell) {
    const int W0r[4] = {0,3,5,8};
    const int W1r[4] = {1,4,6,7};
    const int W2r[4] = {2,2,7,7};
    switch (j) {
    case 0: row = W0r[g]; cell = 0; return true;
    case 1: row = W0r[g]; cell = 1; return true;
    case 2: row = W0r[g]; cell = 2; return true;
    case 3: if (g == 3) { row = 7; cell = 2; } else { row = W1r[g]; cell = 0; } return true;
    case 4: if (g == 3) return false; row = W1r[g]; cell = 1; return true;
    case 5: if (g == 3) return false; row = W1r[g]; cell = 2; return true;
    case 6: if (g == 1) { row = 2; cell = 2; return true; }
            if (g == 3) return false; row = W2r[g]; cell = 0; return true;
    default: if (g == 0) { row = 2; cell = 1; return true; }
             if (g == 2) { row = 7; cell = 1; return true; }
             return false;
    }
}

// Wa[(m,T,lane,i)] = bf16 W[ch=T*16+(lane&15)][m, tap(g=lane>>4, j=i)] or 0
__global__ void prep_kernel(const float* __restrict__ W, const float* __restrict__ bias,
                            unsigned short* __restrict__ Wa, float* __restrict__ bias32) {
    int idx = blockIdx.x * 256 + threadIdx.x;
    if (idx < 3072) {
        int i  = idx & 7;
        int l  = (idx >> 3) & 63;
        int T  = (idx >> 9) & 1;
        int mm = idx >> 10;
        int ch = T * 16 + (l & 15);
        int g  = l >> 4;
        int row, cell;
        float w = 0.f;
        if (ch < 27 && slot_tap(g, i, row, cell)) {
            int di = row / 3, dj = row % 3;
            w = W[ch * 81 + mm * 27 + di * 9 + dj * 3 + cell];
        }
        Wa[idx] = f2bf(w);
    } else if (idx < 3072 + 32) {
        int c = idx - 3072;
        bias32[c] = (c < 27) ? bias[c] : 0.f;
    }
}

static __device__ __forceinline__ float red16_32(float y) {
#if __has_builtin(__builtin_amdgcn_permlane16_swap) && __has_builtin(__builtin_amdgcn_permlane32_swap)
    typedef unsigned uv2 __attribute__((ext_vector_type(2)));
    unsigned a = __float_as_uint(y);
    uv2 r = __builtin_amdgcn_permlane16_swap(a, a, false, false);
    y = __uint_as_float(r[0]) + __uint_as_float(r[1]);
    a = __float_as_uint(y);
    uv2 q = __builtin_amdgcn_permlane32_swap(a, a, false, false);
    return __uint_as_float(q[0]) + __uint_as_float(q[1]);
#else
    y += __shfl_xor(y, 16);
    y += __shfl_xor(y, 32);
    return y;
#endif
}

__global__ __launch_bounds__(512) void invo_mfma_kernel(
    const float* __restrict__ img,   // (3, D,H,W) f32
    const float* __restrict__ x,     // (4, 1, D,H,W) f32
    const unsigned short* __restrict__ Wa,
    const float* __restrict__ bias32,
    float* __restrict__ out)         // (4, 1, D,H,W) f32
{
    __shared__ unsigned short sImg[3 * PLANE];   // bf16 halo planes [m][cell]
    __shared__ uint2 sX2[HALO];                  // f16 [cell][b01, b23]

    // XCD-aware bijective swizzle: 2048 blocks = 8 XCDs x 256-chunk
    const unsigned orig = blockIdx.x;
    const unsigned wg = ((orig & 7u) << 8) | (orig >> 3);
    const int w0 = (wg & 7) * TW;
    const int h0 = ((wg >> 3) & 15) * TH;
    const int d0 = (wg >> 7) * TD;
    const int tid = threadIdx.x;

    // ---- stage halos ----
    for (int idx = tid; idx < PLANE; idx += 512) {
        if (idx < HALO) {
            int lw = idx % HW;
            int t  = idx / HW;
            int lh = t % HH;
            int ld = t / HH;
            int gd = d0 - 1 + ld, gh = h0 - 1 + lh, gw = w0 - 1 + lw;
            bool ok = (unsigned)gd < DIM && (unsigned)gh < DIM && (unsigned)gw < DIM;
            long gi = ((long)gd * DIM + gh) * DIM + gw;
            float i0 = 0, i1 = 0, i2 = 0, x0 = 0, x1 = 0, x2 = 0, x3 = 0;
            if (ok) {
                i0 = img[gi]; i1 = img[NVOX + gi]; i2 = img[2 * NVOX + gi];
                x0 = x[gi]; x1 = x[NVOX + gi]; x2 = x[2 * NVOX + gi]; x3 = x[3 * NVOX + gi];
            }
            // hw bf16 pack (RNE, same as f2bf) -- 2 instr instead of ~13
            unsigned i01, i22;
            asm("v_cvt_pk_bf16_f32 %0, %1, %2" : "=v"(i01) : "v"(i0), "v"(i1));
            asm("v_cvt_pk_bf16_f32 %0, %1, %2" : "=v"(i22) : "v"(i2), "v"(i2));
            sImg[idx]             = (unsigned short)(i01 & 0xffffu);
            sImg[PLANE + idx]     = (unsigned short)(i01 >> 16);
            sImg[2 * PLANE + idx] = (unsigned short)(i22 & 0xffffu);
            unsigned p01 = __builtin_bit_cast(unsigned, __builtin_amdgcn_cvt_pkrtz(x0, x1));
            unsigned p23 = __builtin_bit_cast(unsigned, __builtin_amdgcn_cvt_pkrtz(x2, x3));
            sX2[idx] = make_uint2(p01, p23);
        } else {
            sImg[idx] = 0; sImg[PLANE + idx] = 0; sImg[2 * PLANE + idx] = 0;  // guard
        }
    }
    __syncthreads();

    const int lane = tid & 63;
    const int wv   = tid >> 6;       // wave 0..7
    const int v    = lane & 15;      // voxel (w) within 16-run
    const int g    = lane >> 4;      // k-group 0..3
    const unsigned b = 2u * (v & 1);

    // v_perm selectors for B-frag gather (hi, lo sources; code = byte pos in 8B window)
    unsigned sel0 = b | ((b + 1) << 8) | ((b + 2) << 16) | ((b + 3) << 24);
    unsigned sel1 = (4 + b) | ((5 + b) << 8) | (b << 16) | ((b + 1) << 24);
    unsigned sel2 = (b + 2) | ((b + 3) << 8) | ((b + 4) << 16) | ((b + 5) << 24);
    unsigned sel3 = (g == 1) ? ((b + 4) | ((b + 5) << 8) | ((b + 4) << 16) | ((b + 5) << 24)) : sel0;

    // window rows per group
    const int w0r = (g == 0) ? 0 : (g == 1) ? 3 : (g == 2) ? 5 : 8;
    const int w1r = (g == 0) ? 1 : (g == 1) ? 4 : (g == 2) ? 6 : 7;
    const int w2r = (g < 2) ? 2 : 7;

    const int e  = v & ~1;
    const int e1 = (g == 3) ? ((v + 2) & ~1) : e;   // g3's W1 window shifted +2 cells

    // m=0 window dword offsets only; m=1,2 become compile-time +904/+1808 dword
    // immediates on the ds_read (folds into the 16-bit offset field)
    int wkd0[3];
    wkd0[0] = ((w0r / 3) * (HH * HW) + (w0r % 3) * HW + e) / 2;
    wkd0[1] = ((w1r / 3) * (HH * HW) + (w1r % 3) * HW + e1) / 2;
    wkd0[2] = ((w2r / 3) * (HH * HW) + (w2r % 3) * HW + e) / 2;

    // apply-step x cell offsets for this lane's channels
    int xo0[4], xo1[4];
    #pragma unroll
    for (int r = 0; r < 4; ++r) {
        int c = 4 * g + r;
        { int i3 = c / 9, rr = c - 9 * i3, j3 = rr / 3, k3 = rr - 3 * j3;
          xo0[r] = i3 * (HH * HW) + j3 * HW + k3; }
        int c1 = 16 + 4 * g + r;
        if (c1 < 27) {
            int i3 = c1 / 9, rr = c1 - 9 * i3, j3 = rr / 3, k3 = rr - 3 * j3;
            xo1[r] = i3 * (HH * HW) + j3 * HW + k3;
        } else xo1[r] = 0;
    }

    // hoist A fragments + bias
    bf16x8 afrag[3][2];
    #pragma unroll
    for (int m = 0; m < 3; ++m)
        #pragma unroll
        for (int T = 0; T < 2; ++T)
            afrag[m][T] = *reinterpret_cast<const bf16x8*>(&Wa[((m * 2 + T) * 64 + lane) * 8]);
    f32x4 b0 = *reinterpret_cast<const f32x4*>(&bias32[4 * g]);
    f32x4 b1 = *reinterpret_cast<const f32x4*>(&bias32[16 + 4 * g]);

    const unsigned* s32 = reinterpret_cast<const unsigned*>(sImg);

    #pragma unroll 1
    for (int it = 0; it < 8; ++it) {
        const int run = wv * 8 + it;             // 0..63; ld = wv, lh = it
        const int ld = run >> 3, lh = run & 7;
        const int rdw   = (ld * HH + lh) * (HW / 2);
        const int xbase = (ld * HH + lh) * HW + v;

        f32x4 acc0 = b0, acc1 = b1;    // bias folded into accumulator init
        #pragma unroll
        for (int m = 0; m < 3; ++m) {
            const int mo = m * (PLANE / 2);      // compile-time: 0, 904, 1808 dwords
            unsigned lo0 = s32[rdw + wkd0[0] + mo], hi0 = s32[rdw + wkd0[0] + mo + 1];
            unsigned lo1 = s32[rdw + wkd0[1] + mo], hi1 = s32[rdw + wkd0[1] + mo + 1];
            unsigned lo2 = s32[rdw + wkd0[2] + mo], hi2 = s32[rdw + wkd0[2] + mo + 1];
            unsigned d0p = __builtin_amdgcn_perm(hi0, lo0, sel0);
            unsigned d1p = __builtin_amdgcn_perm(hi0, lo1, sel1);
            unsigned d2p = __builtin_amdgcn_perm(hi1, lo1, sel2);
            unsigned d3p = __builtin_amdgcn_perm(hi2, lo2, sel3);
            uintx4 uu = {d0p, d1p, d2p, d3p};
            bf16x8 bfrag = __builtin_bit_cast(bf16x8, uu);
            acc0 = __builtin_amdgcn_mfma_f32_16x16x32_bf16(afrag[m][0], bfrag, acc0, 0, 0, 0);
            acc1 = __builtin_amdgcn_mfma_f32_16x16x32_bf16(afrag[m][1], bfrag, acc1, 0, 0, 0);
        }

        // apply: y[b] = sum_ch K[ch] * x[b, p+off(ch)]  -- f16 dot2 path
        float y0 = 0, y1 = 0, y2 = 0, y3 = 0;
#if __has_builtin(__builtin_amdgcn_fdot2)
        #pragma unroll
        for (int r = 0; r < 4; r += 2) {
            {
                half2t kp = __builtin_bit_cast(half2t, __builtin_amdgcn_cvt_pkrtz(acc0[r], acc0[r + 1]));
                uint2 uA = sX2[xbase + xo0[r]];
                uint2 uB = sX2[xbase + xo0[r + 1]];
                unsigned p0 = __builtin_amdgcn_perm(uB.x, uA.x, 0x05040100u);
                unsigned p1 = __builtin_amdgcn_perm(uB.x, uA.x, 0x07060302u);
                unsigned p2 = __builtin_amdgcn_perm(uB.y, uA.y, 0x05040100u);
                unsigned p3 = __builtin_amdgcn_perm(uB.y, uA.y, 0x07060302u);
                y0 = __builtin_amdgcn_fdot2(kp, __builtin_bit_cast(half2t, p0), y0, false);
                y1 = __builtin_amdgcn_fdot2(kp, __builtin_bit_cast(half2t, p1), y1, false);
                y2 = __builtin_amdgcn_fdot2(kp, __builtin_bit_cast(half2t, p2), y2, false);
                y3 = __builtin_amdgcn_fdot2(kp, __builtin_bit_cast(half2t, p3), y3, false);
            }
            {
                half2t kp = __builtin_bit_cast(half2t, __builtin_amdgcn_cvt_pkrtz(acc1[r], acc1[r + 1]));
                uint2 uA = sX2[xbase + xo1[r]];
                uint2 uB = sX2[xbase + xo1[r + 1]];
                unsigned p0 = __builtin_amdgcn_perm(uB.x, uA.x, 0x05040100u);
                unsigned p1 = __builtin_amdgcn_perm(uB.x, uA.x, 0x07060302u);
                unsigned p2 = __builtin_amdgcn_perm(uB.y, uA.y, 0x05040100u);
                unsigned p3 = __builtin_amdgcn_perm(uB.y, uA.y, 0x07060302u);
                y0 = __builtin_amdgcn_fdot2(kp, __builtin_bit_cast(half2t, p0), y0, false);
                y1 = __builtin_amdgcn_fdot2(kp, __builtin_bit_cast(half2t, p1), y1, false);
                y2 = __builtin_amdgcn_fdot2(kp, __builtin_bit_cast(half2t, p2), y2, false);
                y3 = __builtin_amdgcn_fdot2(kp, __builtin_bit_cast(half2t, p3), y3, false);
            }
        }
#else
        #pragma unroll
        for (int r = 0; r < 4; ++r) {
            float K0 = acc0[r];
            float K1 = acc1[r];
            uint2 u0 = sX2[xbase + xo0[r]];
            uint2 u1 = sX2[xbase + xo1[r]];
            half2t a0 = __builtin_bit_cast(half2t, u0.x), a1 = __builtin_bit_cast(half2t, u0.y);
            half2t c0 = __builtin_bit_cast(half2t, u1.x), c1 = __builtin_bit_cast(half2t, u1.y);
            y0 = fmaf(K0, (float)a0[0], y0); y1 = fmaf(K0, (float)a0[1], y1);
            y2 = fmaf(K0, (float)a1[0], y2); y3 = fmaf(K0, (float)a1[1], y3);
            y0 = fmaf(K1, (float)c0[0], y0); y1 = fmaf(K1, (float)c0[1], y1);
            y2 = fmaf(K1, (float)c1[0], y2); y3 = fmaf(K1, (float)c1[1], y3);
        }
#endif

        y0 = red16_32(y0); y1 = red16_32(y1); y2 = red16_32(y2); y3 = red16_32(y3);

        const long p = ((long)(d0 + ld) * DIM + (h0 + lh)) * DIM + (w0 + v);
        float yv = (g == 0) ? y0 : (g == 1) ? y1 : (g == 2) ? y2 : y3;
        out[(long)g * NVOX + p] = yv;
    }
}

extern "C" void kernel_launch(void* const* d_in, const int* in_sizes, int n_in,
                              void* d_out, int out_size, void* d_ws, size_t ws_size,
                              hipStream_t stream) {
    const float* img  = (const float*)d_in[0];
    const float* x    = (const float*)d_in[1];
    const float* W    = (const float*)d_in[2];
    const float* bias = (const float*)d_in[3];
    float* out = (float*)d_out;

    unsigned short* Wa = (unsigned short*)d_ws;        // 3072 u16
    float* bias32 = (float*)((char*)d_ws + 6144);      // 32 f32

    prep_kernel<<<13, 256, 0, stream>>>(W, bias, Wa, bias32);

    invo_mfma_kernel<<<2048, 512, 0, stream>>>(img, x, Wa, bias32, out);
}

// Round 12
// 47.434 us; speedup vs baseline: 1.2623x; 1.0165x over previous
//
#include <hip/hip_runtime.h>

#define DIM 128
#define NVOX (DIM*DIM*DIM)
#define TD 8
#define TH 8
#define TW 16
#define HD 10
#define HH 10
#define HW 18
#define HALO (HD*HH*HW)   // 1800
#define PLANE 1808        // + guard cells (zeroed), keeps dword alignment

typedef __attribute__((ext_vector_type(8))) __bf16 bf16x8;
typedef __attribute__((ext_vector_type(4))) float  f32x4;
typedef __attribute__((ext_vector_type(4))) unsigned uintx4;
typedef __attribute__((ext_vector_type(2))) _Float16 half2t;

static __device__ __host__ __forceinline__ unsigned short f2bf(float f) {
    union { float f; unsigned u; } v; v.f = f;
    unsigned r = v.u + 0x7FFFu + ((v.u >> 16) & 1u);   // RNE
    return (unsigned short)(r >> 16);
}

// tap table (bank-conflict-minimized): W0 rows {0,1,2,3}[g], W1 rows {4,5,6,7}[g],
// W2 = row 8 for ALL groups (uniform address -> broadcast), cells g0:(0,1), g1:(2).
static __device__ __forceinline__ bool slot_tap(int g, int j, int& row, int& cell) {
    if (j < 3) { row = g;     cell = j;     return true; }
    if (j < 6) { row = 4 + g; cell = j - 3; return true; }
    if (g == 0)            { row = 8; cell = j - 6; return true; }   // cells 0,1
    if (g == 1 && j == 6)  { row = 8; cell = 2;     return true; }
    return false;   // zero-weight pad
}

// Wa[(m,T,lane,i)] = bf16 W[ch=T*16+(lane&15)][m, tap(g=lane>>4, j=i)] or 0
__global__ void prep_kernel(const float* __restrict__ W, const float* __restrict__ bias,
                            unsigned short* __restrict__ Wa, float* __restrict__ bias32) {
    int idx = blockIdx.x * 256 + threadIdx.x;
    if (idx < 3072) {
        int i  = idx & 7;
        int l  = (idx >> 3) & 63;
        int T  = (idx >> 9) & 1;
        int mm = idx >> 10;
        int ch = T * 16 + (l & 15);
        int g  = l >> 4;
        int row, cell;
        float w = 0.f;
        if (ch < 27 && slot_tap(g, i, row, cell)) {
            int di = row / 3, dj = row % 3;
            w = W[ch * 81 + mm * 27 + di * 9 + dj * 3 + cell];
        }
        Wa[idx] = f2bf(w);
    } else if (idx < 3072 + 32) {
        int c = idx - 3072;
        bias32[c] = (c < 27) ? bias[c] : 0.f;
    }
}

static __device__ __forceinline__ float red16_32(float y) {
#if __has_builtin(__builtin_amdgcn_permlane16_swap) && __has_builtin(__builtin_amdgcn_permlane32_swap)
    typedef unsigned uv2 __attribute__((ext_vector_type(2)));
    unsigned a = __float_as_uint(y);
    uv2 r = __builtin_amdgcn_permlane16_swap(a, a, false, false);
    y = __uint_as_float(r[0]) + __uint_as_float(r[1]);
    a = __float_as_uint(y);
    uv2 q = __builtin_amdgcn_permlane32_swap(a, a, false, false);
    return __uint_as_float(q[0]) + __uint_as_float(q[1]);
#else
    y += __shfl_xor(y, 16);
    y += __shfl_xor(y, 32);
    return y;
#endif
}

__global__ __launch_bounds__(512) void invo_mfma_kernel(
    const float* __restrict__ img,   // (3, D,H,W) f32
    const float* __restrict__ x,     // (4, 1, D,H,W) f32
    const unsigned short* __restrict__ Wa,
    const float* __restrict__ bias32,
    float* __restrict__ out)         // (4, 1, D,H,W) f32
{
    __shared__ unsigned short sImg[3 * PLANE];   // bf16 halo planes [m][cell]
    __shared__ uint2 sX2[HALO];                  // f16 [cell][b01, b23]

    // XCD-aware bijective swizzle: 2048 blocks = 8 XCDs x 256-chunk
    const unsigned orig = blockIdx.x;
    const unsigned wg = ((orig & 7u) << 8) | (orig >> 3);
    const int w0 = (wg & 7) * TW;
    const int h0 = ((wg >> 3) & 15) * TH;
    const int d0 = (wg >> 7) * TD;
    const int tid = threadIdx.x;

    // ---- stage halos ----
    for (int idx = tid; idx < PLANE; idx += 512) {
        if (idx < HALO) {
            int lw = idx % HW;
            int t  = idx / HW;
            int lh = t % HH;
            int ld = t / HH;
            int gd = d0 - 1 + ld, gh = h0 - 1 + lh, gw = w0 - 1 + lw;
            bool ok = (unsigned)gd < DIM && (unsigned)gh < DIM && (unsigned)gw < DIM;
            long gi = ((long)gd * DIM + gh) * DIM + gw;
            float i0 = 0, i1 = 0, i2 = 0, x0 = 0, x1 = 0, x2 = 0, x3 = 0;
            if (ok) {
                i0 = img[gi]; i1 = img[NVOX + gi]; i2 = img[2 * NVOX + gi];
                x0 = x[gi]; x1 = x[NVOX + gi]; x2 = x[2 * NVOX + gi]; x3 = x[3 * NVOX + gi];
            }
            // hw bf16 pack (RNE, same as f2bf)
            unsigned i01, i22;
            asm("v_cvt_pk_bf16_f32 %0, %1, %2" : "=v"(i01) : "v"(i0), "v"(i1));
            asm("v_cvt_pk_bf16_f32 %0, %1, %2" : "=v"(i22) : "v"(i2), "v"(i2));
            sImg[idx]             = (unsigned short)(i01 & 0xffffu);
            sImg[PLANE + idx]     = (unsigned short)(i01 >> 16);
            sImg[2 * PLANE + idx] = (unsigned short)(i22 & 0xffffu);
            unsigned p01 = __builtin_bit_cast(unsigned, __builtin_amdgcn_cvt_pkrtz(x0, x1));
            unsigned p23 = __builtin_bit_cast(unsigned, __builtin_amdgcn_cvt_pkrtz(x2, x3));
            sX2[idx] = make_uint2(p01, p23);
        } else {
            sImg[idx] = 0; sImg[PLANE + idx] = 0; sImg[2 * PLANE + idx] = 0;  // guard
        }
    }
    __syncthreads();

    const int lane = tid & 63;
    const int wv   = tid >> 6;       // wave 0..7
    const int v    = lane & 15;      // voxel (w) within 16-run
    const int g    = lane >> 4;      // k-group 0..3
    const unsigned b = 2u * (v & 1);

    // v_perm selectors for B-frag gather (hi, lo sources; code = byte pos in 8B window)
    unsigned sel0 = b | ((b + 1) << 8) | ((b + 2) << 16) | ((b + 3) << 24);
    unsigned sel1 = (4 + b) | ((5 + b) << 8) | (b << 16) | ((b + 1) << 24);
    unsigned sel2 = (b + 2) | ((b + 3) << 8) | ((b + 4) << 16) | ((b + 5) << 24);
    // W2 slots: g0 cells (0,1) -> sel0 pattern; g1 cell 2 duplicated; g2/g3 don't care
    unsigned sel3 = (g == 1) ? ((4 + b) | ((5 + b) << 8) | ((4 + b) << 16) | ((5 + b) << 24)) : sel0;

    // window rows per group (bank-tiled)
    const int w0r = g;         // rows 0..3  -> bank offsets {0,9,18,26}
    const int w1r = 4 + g;     // rows 4..7  -> bank offsets {3,12,20,29}
    const int w2r = 8;         // row 8 for all -> uniform addr, broadcast

    const int e = v & ~1;

    // m=0 window dword offsets; m=1,2 are +904/+1808 compile-time immediates
    int wkd0[3];
    wkd0[0] = ((w0r / 3) * (HH * HW) + (w0r % 3) * HW + e) / 2;
    wkd0[1] = ((w1r / 3) * (HH * HW) + (w1r % 3) * HW + e) / 2;
    wkd0[2] = ((w2r / 3) * (HH * HW) + (w2r % 3) * HW + e) / 2;

    // apply-step x cell offsets for this lane's channels
    int xo0[4], xo1[4];
    #pragma unroll
    for (int r = 0; r < 4; ++r) {
        int c = 4 * g + r;
        { int i3 = c / 9, rr = c - 9 * i3, j3 = rr / 3, k3 = rr - 3 * j3;
          xo0[r] = i3 * (HH * HW) + j3 * HW + k3; }
        int c1 = 16 + 4 * g + r;
        if (c1 < 27) {
            int i3 = c1 / 9, rr = c1 - 9 * i3, j3 = rr / 3, k3 = rr - 3 * j3;
            xo1[r] = i3 * (HH * HW) + j3 * HW + k3;
        } else xo1[r] = 0;
    }

    // hoist A fragments + bias
    bf16x8 afrag[3][2];
    #pragma unroll
    for (int m = 0; m < 3; ++m)
        #pragma unroll
        for (int T = 0; T < 2; ++T)
            afrag[m][T] = *reinterpret_cast<const bf16x8*>(&Wa[((m * 2 + T) * 64 + lane) * 8]);
    f32x4 b0 = *reinterpret_cast<const f32x4*>(&bias32[4 * g]);
    f32x4 b1 = *reinterpret_cast<const f32x4*>(&bias32[16 + 4 * g]);

    const unsigned* s32 = reinterpret_cast<const unsigned*>(sImg);

    #pragma unroll 1
    for (int it = 0; it < 8; ++it) {
        const int run = wv * 8 + it;             // 0..63; ld = wv, lh = it
        const int ld = run >> 3, lh = run & 7;
        const int rdw   = (ld * HH + lh) * (HW / 2);
        const int xbase = (ld * HH + lh) * HW + v;

        f32x4 acc0 = b0, acc1 = b1;    // bias folded into accumulator init
        #pragma unroll
        for (int m = 0; m < 3; ++m) {
            const int mo = m * (PLANE / 2);      // compile-time: 0, 904, 1808 dwords
            unsigned lo0 = s32[rdw + wkd0[0] + mo], hi0 = s32[rdw + wkd0[0] + mo + 1];
            unsigned lo1 = s32[rdw + wkd0[1] + mo], hi1 = s32[rdw + wkd0[1] + mo + 1];
            unsigned lo2 = s32[rdw + wkd0[2] + mo], hi2 = s32[rdw + wkd0[2] + mo + 1];
            unsigned d0p = __builtin_amdgcn_perm(hi0, lo0, sel0);
            unsigned d1p = __builtin_amdgcn_perm(hi0, lo1, sel1);
            unsigned d2p = __builtin_amdgcn_perm(hi1, lo1, sel2);
            unsigned d3p = __builtin_amdgcn_perm(hi2, lo2, sel3);
            uintx4 uu = {d0p, d1p, d2p, d3p};
            bf16x8 bfrag = __builtin_bit_cast(bf16x8, uu);
            acc0 = __builtin_amdgcn_mfma_f32_16x16x32_bf16(afrag[m][0], bfrag, acc0, 0, 0, 0);
            acc1 = __builtin_amdgcn_mfma_f32_16x16x32_bf16(afrag[m][1], bfrag, acc1, 0, 0, 0);
        }

        // apply: y[b] = sum_ch K[ch] * x[b, p+off(ch)]  -- f16 dot2 path
        float y0 = 0, y1 = 0, y2 = 0, y3 = 0;
#if __has_builtin(__builtin_amdgcn_fdot2)
        #pragma unroll
        for (int r = 0; r < 4; r += 2) {
            {
                half2t kp = __builtin_bit_cast(half2t, __builtin_amdgcn_cvt_pkrtz(acc0[r], acc0[r + 1]));
                uint2 uA = sX2[xbase + xo0[r]];
                uint2 uB = sX2[xbase + xo0[r + 1]];
                unsigned p0 = __builtin_amdgcn_perm(uB.x, uA.x, 0x05040100u);
                unsigned p1 = __builtin_amdgcn_perm(uB.x, uA.x, 0x07060302u);
                unsigned p2 = __builtin_amdgcn_perm(uB.y, uA.y, 0x05040100u);
                unsigned p3 = __builtin_amdgcn_perm(uB.y, uA.y, 0x07060302u);
                y0 = __builtin_amdgcn_fdot2(kp, __builtin_bit_cast(half2t, p0), y0, false);
                y1 = __builtin_amdgcn_fdot2(kp, __builtin_bit_cast(half2t, p1), y1, false);
                y2 = __builtin_amdgcn_fdot2(kp, __builtin_bit_cast(half2t, p2), y2, false);
                y3 = __builtin_amdgcn_fdot2(kp, __builtin_bit_cast(half2t, p3), y3, false);
            }
            {
                half2t kp = __builtin_bit_cast(half2t, __builtin_amdgcn_cvt_pkrtz(acc1[r], acc1[r + 1]));
                uint2 uA = sX2[xbase + xo1[r]];
                uint2 uB = sX2[xbase + xo1[r + 1]];
                unsigned p0 = __builtin_amdgcn_perm(uB.x, uA.x, 0x05040100u);
                unsigned p1 = __builtin_amdgcn_perm(uB.x, uA.x, 0x07060302u);
                unsigned p2 = __builtin_amdgcn_perm(uB.y, uA.y, 0x05040100u);
                unsigned p3 = __builtin_amdgcn_perm(uB.y, uA.y, 0x07060302u);
                y0 = __builtin_amdgcn_fdot2(kp, __builtin_bit_cast(half2t, p0), y0, false);
                y1 = __builtin_amdgcn_fdot2(kp, __builtin_bit_cast(half2t, p1), y1, false);
                y2 = __builtin_amdgcn_fdot2(kp, __builtin_bit_cast(half2t, p2), y2, false);
                y3 = __builtin_amdgcn_fdot2(kp, __builtin_bit_cast(half2t, p3), y3, false);
            }
        }
#else
        #pragma unroll
        for (int r = 0; r < 4; ++r) {
            float K0 = acc0[r];
            float K1 = acc1[r];
            uint2 u0 = sX2[xbase + xo0[r]];
            uint2 u1 = sX2[xbase + xo1[r]];
            half2t a0 = __builtin_bit_cast(half2t, u0.x), a1 = __builtin_bit_cast(half2t, u0.y);
            half2t c0 = __builtin_bit_cast(half2t, u1.x), c1 = __builtin_bit_cast(half2t, u1.y);
            y0 = fmaf(K0, (float)a0[0], y0); y1 = fmaf(K0, (float)a0[1], y1);
            y2 = fmaf(K0, (float)a1[0], y2); y3 = fmaf(K0, (float)a1[1], y3);
            y0 = fmaf(K1, (float)c0[0], y0); y1 = fmaf(K1, (float)c0[1], y1);
            y2 = fmaf(K1, (float)c1[0], y2); y3 = fmaf(K1, (float)c1[1], y3);
        }
#endif

        y0 = red16_32(y0); y1 = red16_32(y1); y2 = red16_32(y2); y3 = red16_32(y3);

        const long p = ((long)(d0 + ld) * DIM + (h0 + lh)) * DIM + (w0 + v);
        float yv = (g == 0) ? y0 : (g == 1) ? y1 : (g == 2) ? y2 : y3;
        out[(long)g * NVOX + p] = yv;
    }
}

extern "C" void kernel_launch(void* const* d_in, const int* in_sizes, int n_in,
                              void* d_out, int out_size, void* d_ws, size_t ws_size,
                              hipStream_t stream) {
    const float* img  = (const float*)d_in[0];
    const float* x    = (const float*)d_in[1];
    const float* W    = (const float*)d_in[2];
    const float* bias = (const float*)d_in[3];
    float* out = (float*)d_out;

    unsigned short* Wa = (unsigned short*)d_ws;        // 3072 u16
    float* bias32 = (float*)((char*)d_ws + 6144);      // 32 f32

    prep_kernel<<<13, 256, 0, stream>>>(W, bias, Wa, bias32);

    invo_mfma_kernel<<<2048, 512, 0, stream>>>(img, x, Wa, bias32, out);
}